// Round 12
// baseline (956.365 us; speedup 1.0000x reference)
//
#include <hip/hip_runtime.h>
#include <stdint.h>

constexpr int kN    = 100000;   // nodes
constexpr int kDOut = 128;      // output dim
constexpr int kDIn  = 256;      // input feature dim
constexpr int kNNZ  = 3200000;  // nnz for both X and A
constexpr float kInvKeep = (float)(1.0 / 0.9);
constexpr int kCopies = 8;      // histogram copies (XCD privatization, proven r11)

// ---------------- RNG (verified round 4: partitionable, bits = o0^o1) -----
__device__ __forceinline__ uint32_t rotl32(uint32_t v, int r) {
  return (v << r) | (v >> (32 - r));
}
__device__ __forceinline__ void threefry2x32(uint32_t k0, uint32_t k1,
                                             uint32_t x0, uint32_t x1,
                                             uint32_t& o0, uint32_t& o1) {
  const uint32_t ks0 = k0, ks1 = k1, ks2 = k0 ^ k1 ^ 0x1BD11BDAu;
  x0 += ks0; x1 += ks1;
#define TF_RND(r) { x0 += x1; x1 = rotl32(x1, (r)); x1 ^= x0; }
  TF_RND(13) TF_RND(15) TF_RND(26) TF_RND(6)
  x0 += ks1; x1 += ks2 + 1u;
  TF_RND(17) TF_RND(29) TF_RND(16) TF_RND(24)
  x0 += ks2; x1 += ks0 + 2u;
  TF_RND(13) TF_RND(15) TF_RND(26) TF_RND(6)
  x0 += ks0; x1 += ks1 + 3u;
  TF_RND(17) TF_RND(29) TF_RND(16) TF_RND(24)
  x0 += ks1; x1 += ks2 + 4u;
  TF_RND(13) TF_RND(15) TF_RND(26) TF_RND(6)
  x0 += ks2; x1 += ks0 + 5u;
#undef TF_RND
  o0 = x0; o1 = x1;
}
__device__ __forceinline__ float keep_mask(uint32_t i) {
  uint32_t o0, o1;
  threefry2x32(0u, 42u, 0u, i, o0, o1);
  uint32_t bits = o0 ^ o1;
  float u = __uint_as_float((bits >> 9) | 0x3f800000u) - 1.0f;
  return floorf(0.9f + u);
}

// ---------------- bf16 helpers (RTNE) --------------------------------------
__device__ __forceinline__ uint32_t f32_to_bf16(float f) {
  uint32_t u = __float_as_uint(f);
  u += 0x7fffu + ((u >> 16) & 1u);
  return u >> 16;
}
__device__ __forceinline__ float bf16lo_to_f32(uint32_t packed) {
  return __uint_as_float(packed << 16);
}
__device__ __forceinline__ float bf16hi_to_f32(uint32_t packed) {
  return __uint_as_float(packed & 0xffff0000u);
}

// ---------------- W pack: f32 [256][128] -> bf16x2 u32 [256][64] -----------
// Same bytes double as row-major bf16 [256][128] for the CSR fallback spmm.
__global__ void wpack_kernel(const float* __restrict__ W, uint32_t* __restrict__ Wp) {
  int i = blockIdx.x * blockDim.x + threadIdx.x;   // pair index
  if (i >= kDIn * (kDOut / 2)) return;
  float w0 = W[2 * i], w1 = W[2 * i + 1];
  Wp[i] = f32_to_bf16(w0) | (f32_to_bf16(w1) << 16);
}

// ---------------- X dense path: scatter-add + skinny GEMM ------------------
__global__ void scatteradd_kernel(const int* __restrict__ rows,
                                  const int* __restrict__ cols,
                                  const float* __restrict__ vals,
                                  float* __restrict__ Xd, int nnz) {
  int e = blockIdx.x * blockDim.x + threadIdx.x;
  if (e >= nnz) return;
  if (keep_mask((uint32_t)e) == 0.0f) return;
  atomicAdd(&Xd[(size_t)rows[e] * kDIn + cols[e]], vals[e] * kInvKeep);
}

// One wave per row; lane owns cols 2*lane, 2*lane+1; W bf16x2 in 64KB LDS.
__global__ void __launch_bounds__(256) gemm_kernel(const float* __restrict__ Xd,
                                                   const uint32_t* __restrict__ Wp,
                                                   uint32_t* __restrict__ hb) {
  __shared__ uint32_t wl[kDIn * (kDOut / 2)];   // 16384 u32 = 64 KB
  const int tid = threadIdx.x;
  for (int i = tid; i < kDIn * (kDOut / 2); i += 256) wl[i] = Wp[i];
  __syncthreads();
  const int row  = blockIdx.x * 4 + (tid >> 6);   // kN % 4 == 0, always valid
  const int lane = tid & 63;
  const float4* xp = (const float4*)(Xd + (size_t)row * kDIn);
  float a0 = 0.0f, a1 = 0.0f;
  #pragma unroll 4
  for (int q = 0; q < kDIn / 4; ++q) {
    float4 x = xp[q];
    uint32_t g0 = wl[(4 * q + 0) * 64 + lane];
    uint32_t g1 = wl[(4 * q + 1) * 64 + lane];
    uint32_t g2 = wl[(4 * q + 2) * 64 + lane];
    uint32_t g3 = wl[(4 * q + 3) * 64 + lane];
    a0 += x.x * bf16lo_to_f32(g0); a1 += x.x * bf16hi_to_f32(g0);
    a0 += x.y * bf16lo_to_f32(g1); a1 += x.y * bf16hi_to_f32(g1);
    a0 += x.z * bf16lo_to_f32(g2); a1 += x.z * bf16hi_to_f32(g2);
    a0 += x.w * bf16lo_to_f32(g3); a1 += x.w * bf16hi_to_f32(g3);
  }
  hb[(size_t)row * 64 + lane] = f32_to_bf16(a0) | (f32_to_bf16(a1) << 16);
}

// ---------------- XCD-privatized histogram (proven round 11) ---------------
template<bool DROPOUT>
__global__ void hist8_kernel(const int* __restrict__ rows, int* __restrict__ cnt8,
                             int nnz) {
  int e = blockIdx.x * blockDim.x + threadIdx.x;
  if (e >= nnz) return;
  if (DROPOUT && keep_mask((uint32_t)e) == 0.0f) return;
  int k = blockIdx.x & (kCopies - 1);
  atomicAdd(&cnt8[k * kN + rows[e]], 1);
}

// ---------------- scan over summed copies ----------------------------------
constexpr int kScanChunk = 2048;   // 256 threads x 8 elems
constexpr int kScanBlk   = (kN + kScanChunk - 1) / kScanChunk;  // 49

__global__ void scan1_kernel(const int* __restrict__ cnt8, int* __restrict__ rowptr,
                             int* __restrict__ partials, int n) {
  __shared__ int sd[256];
  int b = blockIdx.x, t = threadIdx.x;
  int base = b * kScanChunk + t * 8;
  int v[8]; int s = 0;
  #pragma unroll
  for (int k = 0; k < 8; ++k) {
    int idx = base + k;
    int c = 0;
    if (idx < n) {
      #pragma unroll
      for (int j = 0; j < kCopies; ++j) c += cnt8[j * kN + idx];
    }
    v[k] = c; s += c;
  }
  sd[t] = s; __syncthreads();
  #pragma unroll
  for (int off = 1; off < 256; off <<= 1) {
    int x = (t >= off) ? sd[t - off] : 0;
    __syncthreads();
    sd[t] += x;
    __syncthreads();
  }
  if (t == 255) partials[b] = sd[255];
  int run = (t == 0) ? 0 : sd[t - 1];
  #pragma unroll
  for (int k = 0; k < 8; ++k) { int idx = base + k; if (idx < n) rowptr[idx] = run; run += v[k]; }
}

__global__ void scan2_kernel(int* __restrict__ partials, int* __restrict__ rowptr,
                             int nblk, int n) {
  __shared__ int sd[64];
  int t = threadIdx.x;
  sd[t] = (t < nblk) ? partials[t] : 0;
  __syncthreads();
  #pragma unroll
  for (int off = 1; off < 64; off <<= 1) {
    int x = (t >= off) ? sd[t - off] : 0;
    __syncthreads();
    sd[t] += x;
    __syncthreads();
  }
  if (t < nblk) partials[t] = (t == 0) ? 0 : sd[t - 1];
  if (t == 63) rowptr[n] = sd[63];
}

// finalize rowptr; seed SINGLE-copy cursor (round-6 proven scatter scheme)
__global__ void scan3_kernel(int* __restrict__ rowptr, int* __restrict__ cur,
                             const int* __restrict__ partials, int n) {
  int i = blockIdx.x * blockDim.x + threadIdx.x;
  if (i < n) {
    int v = rowptr[i] + partials[i / kScanChunk];
    rowptr[i] = v;
    cur[i] = v;
  }
}

// ---------------- single-cursor scatter (round-6 proven, 190us) ------------
template<bool DROPOUT>
__global__ void scatter_kernel(const int* __restrict__ rows,
                               const int* __restrict__ cols,
                               const float* __restrict__ vals,
                               int* __restrict__ cur,
                               uint2* __restrict__ spack, int nnz) {
  int e = blockIdx.x * blockDim.x + threadIdx.x;
  if (e >= nnz) return;
  float v = vals[e];
  if (DROPOUT) {
    if (keep_mask((uint32_t)e) == 0.0f) return;
    v *= kInvKeep;
  }
  int pos = atomicAdd(&cur[rows[e]], 1);
  uint2 p; p.x = (uint32_t)cols[e]; p.y = __float_as_uint(v);
  spack[pos] = p;
}

// ---------------- CSR SpMM, bf16 B-matrix, 4-deep edge unroll (proven) -----
template<bool OUT_BF16, bool RELU>
__global__ void spmm_csr_kernel(const int* __restrict__ rowptr,
                                const uint2* __restrict__ spack,
                                const uint16_t* __restrict__ B,  // bf16 [*, kDOut]
                                void* __restrict__ outv, int nrows) {
  int tid = threadIdx.x;
  int row = blockIdx.x * 4 + (tid >> 6);
  int lane = tid & 63;
  if (row >= nrows) return;
  int e = rowptr[row], e_end = rowptr[row + 1];
  float a0 = 0.0f, a1 = 0.0f;
  const int doff = lane * 2;
  for (; e + 3 < e_end; e += 4) {
    uint2 p0 = spack[e],     p1 = spack[e + 1];
    uint2 p2 = spack[e + 2], p3 = spack[e + 3];
    uint32_t g0 = *(const uint32_t*)(B + (size_t)p0.x * kDOut + doff);
    uint32_t g1 = *(const uint32_t*)(B + (size_t)p1.x * kDOut + doff);
    uint32_t g2 = *(const uint32_t*)(B + (size_t)p2.x * kDOut + doff);
    uint32_t g3 = *(const uint32_t*)(B + (size_t)p3.x * kDOut + doff);
    float v0 = __uint_as_float(p0.y), v1 = __uint_as_float(p1.y);
    float v2 = __uint_as_float(p2.y), v3 = __uint_as_float(p3.y);
    a0 += v0 * bf16lo_to_f32(g0); a1 += v0 * bf16hi_to_f32(g0);
    a0 += v1 * bf16lo_to_f32(g1); a1 += v1 * bf16hi_to_f32(g1);
    a0 += v2 * bf16lo_to_f32(g2); a1 += v2 * bf16hi_to_f32(g2);
    a0 += v3 * bf16lo_to_f32(g3); a1 += v3 * bf16hi_to_f32(g3);
  }
  for (; e < e_end; ++e) {
    uint2 p0 = spack[e];
    float v0 = __uint_as_float(p0.y);
    uint32_t g0 = *(const uint32_t*)(B + (size_t)p0.x * kDOut + doff);
    a0 += v0 * bf16lo_to_f32(g0);
    a1 += v0 * bf16hi_to_f32(g0);
  }
  if (RELU) { a0 = fmaxf(a0, 0.0f); a1 = fmaxf(a1, 0.0f); }
  if (OUT_BF16) {
    uint32_t packed = f32_to_bf16(a0) | (f32_to_bf16(a1) << 16);
    ((uint32_t*)outv)[(size_t)row * (kDOut / 2) + lane] = packed;
  } else {
    float2 o; o.x = a0; o.y = a1;
    ((float2*)outv)[(size_t)row * (kDOut / 2) + lane] = o;
  }
}

// ---------------------------------------------------------------------------
extern "C" void kernel_launch(void* const* d_in, const int* in_sizes, int n_in,
                              void* d_out, int out_size, void* d_ws, size_t ws_size,
                              hipStream_t stream) {
  const int*   x_rows   = (const int*)d_in[0];
  const int*   x_cols   = (const int*)d_in[1];
  const float* x_vals   = (const float*)d_in[2];
  const int*   adj_rows = (const int*)d_in[3];
  const int*   adj_cols = (const int*)d_in[4];
  const float* adj_vals = (const float*)d_in[5];
  const float* W        = (const float*)d_in[6];
  float* out = (float*)d_out;

  // workspace layout (256B-aligned chunks)
  size_t off = 0;
  auto take = [&](size_t bytes) -> char* {
    char* p = (char*)d_ws + off;
    off += (bytes + 255) & ~(size_t)255;
    return p;
  };
  uint16_t* hb     = (uint16_t*)take((size_t)kN * kDOut * 2);       // 25.6 MB
  uint32_t* Wp     = (uint32_t*)take((size_t)kDIn * (kDOut / 2) * 4); // 64 KB
  int*      rowptr = (int*)take((size_t)(kN + 1) * 4);              // 400 KB
  int*      cnt8   = (int*)take((size_t)kCopies * kN * 4);          // 3.2 MB
  int*      cur    = (int*)take((size_t)kN * 4);                    // 400 KB
  int*      partials = (int*)take(64 * 4);
  uint2*    spack  = (uint2*)take((size_t)kNNZ * 8);                // 25.6 MB
  const size_t csrNeeded = off;                                     // ~55.3 MB
  float*    Xd     = (float*)take((size_t)kN * kDIn * 4);           // 102.4 MB
  const size_t fullNeeded = off;                                    // ~157.7 MB
  if (ws_size < csrNeeded) return;
  const bool dense = (ws_size >= fullNeeded);

  const int edgeBlocks = (kNNZ + 255) / 256;
  const int spmmBlocks = (kN + 3) / 4;

  wpack_kernel<<<(kDIn * (kDOut / 2) + 255) / 256, 256, 0, stream>>>(W, Wp);

  // ---------- X: h = dropout(X) @ W -> hb (bf16) ----------
  if (dense) {
    hipMemsetAsync(Xd, 0, (size_t)kN * kDIn * 4, stream);
    scatteradd_kernel<<<edgeBlocks, 256, 0, stream>>>(x_rows, x_cols, x_vals, Xd, kNNZ);
    gemm_kernel<<<kN / 4, 256, 0, stream>>>(Xd, Wp, (uint32_t*)hb);
  } else {
    hipMemsetAsync(cnt8, 0, (size_t)kCopies * kN * 4, stream);
    hist8_kernel<true><<<edgeBlocks, 256, 0, stream>>>(x_rows, cnt8, kNNZ);
    scan1_kernel<<<kScanBlk, 256, 0, stream>>>(cnt8, rowptr, partials, kN);
    scan2_kernel<<<1, 64, 0, stream>>>(partials, rowptr, kScanBlk, kN);
    scan3_kernel<<<(kN + 255) / 256, 256, 0, stream>>>(rowptr, cur, partials, kN);
    scatter_kernel<true><<<edgeBlocks, 256, 0, stream>>>(
        x_rows, x_cols, x_vals, cur, spack, kNNZ);
    spmm_csr_kernel<true, false><<<spmmBlocks, 256, 0, stream>>>(
        rowptr, spack, (const uint16_t*)Wp, hb, kN);
  }

  // ---------- adj: CSR build (hist8 + single-cur scatter) + spmm2(+relu) ----
  hipMemsetAsync(cnt8, 0, (size_t)kCopies * kN * 4, stream);
  hist8_kernel<false><<<edgeBlocks, 256, 0, stream>>>(adj_rows, cnt8, kNNZ);
  scan1_kernel<<<kScanBlk, 256, 0, stream>>>(cnt8, rowptr, partials, kN);
  scan2_kernel<<<1, 64, 0, stream>>>(partials, rowptr, kScanBlk, kN);
  scan3_kernel<<<(kN + 255) / 256, 256, 0, stream>>>(rowptr, cur, partials, kN);
  scatter_kernel<false><<<edgeBlocks, 256, 0, stream>>>(
      adj_rows, adj_cols, adj_vals, cur, spack, kNNZ);
  spmm_csr_kernel<false, true><<<spmmBlocks, 256, 0, stream>>>(
      rowptr, spack, hb, out, kN);
}

// Round 13
// 841.527 us; speedup vs baseline: 1.1365x; 1.1365x over previous
//
#include <hip/hip_runtime.h>
#include <stdint.h>

constexpr int kN    = 100000;   // nodes
constexpr int kDOut = 128;      // output dim
constexpr int kDIn  = 256;      // input feature dim
constexpr int kNNZ  = 3200000;  // nnz for both X and A
constexpr float kInvKeep = (float)(1.0 / 0.9);
constexpr int kCopies = 8;      // histogram copies (XCD privatization, proven r11)

// ---------------- RNG (verified round 4: partitionable, bits = o0^o1) -----
__device__ __forceinline__ uint32_t rotl32(uint32_t v, int r) {
  return (v << r) | (v >> (32 - r));
}
__device__ __forceinline__ void threefry2x32(uint32_t k0, uint32_t k1,
                                             uint32_t x0, uint32_t x1,
                                             uint32_t& o0, uint32_t& o1) {
  const uint32_t ks0 = k0, ks1 = k1, ks2 = k0 ^ k1 ^ 0x1BD11BDAu;
  x0 += ks0; x1 += ks1;
#define TF_RND(r) { x0 += x1; x1 = rotl32(x1, (r)); x1 ^= x0; }
  TF_RND(13) TF_RND(15) TF_RND(26) TF_RND(6)
  x0 += ks1; x1 += ks2 + 1u;
  TF_RND(17) TF_RND(29) TF_RND(16) TF_RND(24)
  x0 += ks2; x1 += ks0 + 2u;
  TF_RND(13) TF_RND(15) TF_RND(26) TF_RND(6)
  x0 += ks0; x1 += ks1 + 3u;
  TF_RND(17) TF_RND(29) TF_RND(16) TF_RND(24)
  x0 += ks1; x1 += ks2 + 4u;
  TF_RND(13) TF_RND(15) TF_RND(26) TF_RND(6)
  x0 += ks2; x1 += ks0 + 5u;
#undef TF_RND
  o0 = x0; o1 = x1;
}
__device__ __forceinline__ float keep_mask(uint32_t i) {
  uint32_t o0, o1;
  threefry2x32(0u, 42u, 0u, i, o0, o1);
  uint32_t bits = o0 ^ o1;
  float u = __uint_as_float((bits >> 9) | 0x3f800000u) - 1.0f;
  return floorf(0.9f + u);
}

// ---------------- bf16 helpers (RTNE) --------------------------------------
__device__ __forceinline__ uint32_t f32_to_bf16(float f) {
  uint32_t u = __float_as_uint(f);
  u += 0x7fffu + ((u >> 16) & 1u);
  return u >> 16;
}
__device__ __forceinline__ float bf16lo_to_f32(uint32_t packed) {
  return __uint_as_float(packed << 16);
}
__device__ __forceinline__ float bf16hi_to_f32(uint32_t packed) {
  return __uint_as_float(packed & 0xffff0000u);
}

// ---------------- W pack: f32 [256][128] -> bf16x2 u32 [256][64] -----------
__global__ void wpack_kernel(const float* __restrict__ W, uint32_t* __restrict__ Wp) {
  int i = blockIdx.x * blockDim.x + threadIdx.x;   // pair index
  if (i >= kDIn * (kDOut / 2)) return;
  float w0 = W[2 * i], w1 = W[2 * i + 1];
  Wp[i] = f32_to_bf16(w0) | (f32_to_bf16(w1) << 16);
}

// ---------------- X dense path: scatter-add + skinny GEMM ------------------
__global__ void scatteradd_kernel(const int* __restrict__ rows,
                                  const int* __restrict__ cols,
                                  const float* __restrict__ vals,
                                  float* __restrict__ Xd, int nnz) {
  int e = blockIdx.x * blockDim.x + threadIdx.x;
  if (e >= nnz) return;
  if (keep_mask((uint32_t)e) == 0.0f) return;
  atomicAdd(&Xd[(size_t)rows[e] * kDIn + cols[e]], vals[e] * kInvKeep);
}

// 1024 threads = 16 waves = 16 rows/block; 64KB LDS for W; lane owns 2 cols.
// Occupancy fix vs r12: 16 rows amortize the LDS fill, 1024 thr/block lifts
// threads/CU from 512 (22%) to >=1024.
__global__ void __launch_bounds__(1024) gemm_kernel(const float* __restrict__ Xd,
                                                    const uint32_t* __restrict__ Wp,
                                                    uint32_t* __restrict__ hb) {
  __shared__ uint32_t wl[kDIn * (kDOut / 2)];   // 16384 u32 = 64 KB
  const int tid = threadIdx.x;
  #pragma unroll
  for (int i = 0; i < 16; ++i) wl[i * 1024 + tid] = Wp[i * 1024 + tid];
  __syncthreads();
  const int row  = blockIdx.x * 16 + (tid >> 6);   // kN % 16 == 0
  const int lane = tid & 63;
  const float4* xp = (const float4*)(Xd + (size_t)row * kDIn);
  float a0 = 0.0f, a1 = 0.0f;
  #pragma unroll 2
  for (int q = 0; q < kDIn / 4; ++q) {
    float4 x = xp[q];
    uint32_t g0 = wl[(4 * q + 0) * 64 + lane];
    uint32_t g1 = wl[(4 * q + 1) * 64 + lane];
    uint32_t g2 = wl[(4 * q + 2) * 64 + lane];
    uint32_t g3 = wl[(4 * q + 3) * 64 + lane];
    a0 += x.x * bf16lo_to_f32(g0); a1 += x.x * bf16hi_to_f32(g0);
    a0 += x.y * bf16lo_to_f32(g1); a1 += x.y * bf16hi_to_f32(g1);
    a0 += x.z * bf16lo_to_f32(g2); a1 += x.z * bf16hi_to_f32(g2);
    a0 += x.w * bf16lo_to_f32(g3); a1 += x.w * bf16hi_to_f32(g3);
  }
  hb[(size_t)row * 64 + lane] = f32_to_bf16(a0) | (f32_to_bf16(a1) << 16);
}

// ---------------- XCD-privatized histogram (proven round 11) ---------------
template<bool DROPOUT>
__global__ void hist8_kernel(const int* __restrict__ rows, int* __restrict__ cnt8,
                             int nnz) {
  int e = blockIdx.x * blockDim.x + threadIdx.x;
  if (e >= nnz) return;
  if (DROPOUT && keep_mask((uint32_t)e) == 0.0f) return;
  int k = blockIdx.x & (kCopies - 1);
  atomicAdd(&cnt8[k * kN + rows[e]], 1);
}

// ---------------- scan over summed copies ----------------------------------
constexpr int kScanChunk = 2048;   // 256 threads x 8 elems
constexpr int kScanBlk   = (kN + kScanChunk - 1) / kScanChunk;  // 49

__global__ void scan1_kernel(const int* __restrict__ cnt8, int* __restrict__ rowptr,
                             int* __restrict__ partials, int n) {
  __shared__ int sd[256];
  int b = blockIdx.x, t = threadIdx.x;
  int base = b * kScanChunk + t * 8;
  int v[8]; int s = 0;
  #pragma unroll
  for (int k = 0; k < 8; ++k) {
    int idx = base + k;
    int c = 0;
    if (idx < n) {
      #pragma unroll
      for (int j = 0; j < kCopies; ++j) c += cnt8[j * kN + idx];
    }
    v[k] = c; s += c;
  }
  sd[t] = s; __syncthreads();
  #pragma unroll
  for (int off = 1; off < 256; off <<= 1) {
    int x = (t >= off) ? sd[t - off] : 0;
    __syncthreads();
    sd[t] += x;
    __syncthreads();
  }
  if (t == 255) partials[b] = sd[255];
  int run = (t == 0) ? 0 : sd[t - 1];
  #pragma unroll
  for (int k = 0; k < 8; ++k) { int idx = base + k; if (idx < n) rowptr[idx] = run; run += v[k]; }
}

__global__ void scan2_kernel(int* __restrict__ partials, int* __restrict__ rowptr,
                             int nblk, int n) {
  __shared__ int sd[64];
  int t = threadIdx.x;
  sd[t] = (t < nblk) ? partials[t] : 0;
  __syncthreads();
  #pragma unroll
  for (int off = 1; off < 64; off <<= 1) {
    int x = (t >= off) ? sd[t - off] : 0;
    __syncthreads();
    sd[t] += x;
    __syncthreads();
  }
  if (t < nblk) partials[t] = (t == 0) ? 0 : sd[t - 1];
  if (t == 63) rowptr[n] = sd[63];
}

__global__ void scan3_kernel(int* __restrict__ rowptr, int* __restrict__ cur,
                             const int* __restrict__ partials, int n) {
  int i = blockIdx.x * blockDim.x + threadIdx.x;
  if (i < n) {
    int v = rowptr[i] + partials[i / kScanChunk];
    rowptr[i] = v;
    cur[i] = v;
  }
}

// ---------------- single-cursor scatter (round-6 proven) -------------------
template<bool DROPOUT>
__global__ void scatter_kernel(const int* __restrict__ rows,
                               const int* __restrict__ cols,
                               const float* __restrict__ vals,
                               int* __restrict__ cur,
                               uint2* __restrict__ spack, int nnz) {
  int e = blockIdx.x * blockDim.x + threadIdx.x;
  if (e >= nnz) return;
  float v = vals[e];
  if (DROPOUT) {
    if (keep_mask((uint32_t)e) == 0.0f) return;
    v *= kInvKeep;
  }
  int pos = atomicAdd(&cur[rows[e]], 1);
  uint2 p; p.x = (uint32_t)cols[e]; p.y = __float_as_uint(v);
  spack[pos] = p;
}

// ---------------- CSR SpMM, bf16 B-matrix, 8-deep edge unroll --------------
template<bool OUT_BF16, bool RELU>
__global__ void spmm_csr_kernel(const int* __restrict__ rowptr,
                                const uint2* __restrict__ spack,
                                const uint16_t* __restrict__ B,  // bf16 [*, kDOut]
                                void* __restrict__ outv, int nrows) {
  int tid = threadIdx.x;
  int row = blockIdx.x * 4 + (tid >> 6);
  int lane = tid & 63;
  if (row >= nrows) return;
  int e = rowptr[row], e_end = rowptr[row + 1];
  float a0 = 0.0f, a1 = 0.0f;
  const int doff = lane * 2;
  for (; e + 7 < e_end; e += 8) {
    uint2 p0 = spack[e],     p1 = spack[e + 1];
    uint2 p2 = spack[e + 2], p3 = spack[e + 3];
    uint2 p4 = spack[e + 4], p5 = spack[e + 5];
    uint2 p6 = spack[e + 6], p7 = spack[e + 7];
    uint32_t g0 = *(const uint32_t*)(B + (size_t)p0.x * kDOut + doff);
    uint32_t g1 = *(const uint32_t*)(B + (size_t)p1.x * kDOut + doff);
    uint32_t g2 = *(const uint32_t*)(B + (size_t)p2.x * kDOut + doff);
    uint32_t g3 = *(const uint32_t*)(B + (size_t)p3.x * kDOut + doff);
    uint32_t g4 = *(const uint32_t*)(B + (size_t)p4.x * kDOut + doff);
    uint32_t g5 = *(const uint32_t*)(B + (size_t)p5.x * kDOut + doff);
    uint32_t g6 = *(const uint32_t*)(B + (size_t)p6.x * kDOut + doff);
    uint32_t g7 = *(const uint32_t*)(B + (size_t)p7.x * kDOut + doff);
    float v0 = __uint_as_float(p0.y), v1 = __uint_as_float(p1.y);
    float v2 = __uint_as_float(p2.y), v3 = __uint_as_float(p3.y);
    float v4 = __uint_as_float(p4.y), v5 = __uint_as_float(p5.y);
    float v6 = __uint_as_float(p6.y), v7 = __uint_as_float(p7.y);
    a0 += v0 * bf16lo_to_f32(g0); a1 += v0 * bf16hi_to_f32(g0);
    a0 += v1 * bf16lo_to_f32(g1); a1 += v1 * bf16hi_to_f32(g1);
    a0 += v2 * bf16lo_to_f32(g2); a1 += v2 * bf16hi_to_f32(g2);
    a0 += v3 * bf16lo_to_f32(g3); a1 += v3 * bf16hi_to_f32(g3);
    a0 += v4 * bf16lo_to_f32(g4); a1 += v4 * bf16hi_to_f32(g4);
    a0 += v5 * bf16lo_to_f32(g5); a1 += v5 * bf16hi_to_f32(g5);
    a0 += v6 * bf16lo_to_f32(g6); a1 += v6 * bf16hi_to_f32(g6);
    a0 += v7 * bf16lo_to_f32(g7); a1 += v7 * bf16hi_to_f32(g7);
  }
  for (; e < e_end; ++e) {
    uint2 p0 = spack[e];
    float v0 = __uint_as_float(p0.y);
    uint32_t g0 = *(const uint32_t*)(B + (size_t)p0.x * kDOut + doff);
    a0 += v0 * bf16lo_to_f32(g0);
    a1 += v0 * bf16hi_to_f32(g0);
  }
  if (RELU) { a0 = fmaxf(a0, 0.0f); a1 = fmaxf(a1, 0.0f); }
  if (OUT_BF16) {
    uint32_t packed = f32_to_bf16(a0) | (f32_to_bf16(a1) << 16);
    ((uint32_t*)outv)[(size_t)row * (kDOut / 2) + lane] = packed;
  } else {
    float2 o; o.x = a0; o.y = a1;
    ((float2*)outv)[(size_t)row * (kDOut / 2) + lane] = o;
  }
}

// ---------------------------------------------------------------------------
extern "C" void kernel_launch(void* const* d_in, const int* in_sizes, int n_in,
                              void* d_out, int out_size, void* d_ws, size_t ws_size,
                              hipStream_t stream) {
  const int*   x_rows   = (const int*)d_in[0];
  const int*   x_cols   = (const int*)d_in[1];
  const float* x_vals   = (const float*)d_in[2];
  const int*   adj_rows = (const int*)d_in[3];
  const int*   adj_cols = (const int*)d_in[4];
  const float* adj_vals = (const float*)d_in[5];
  const float* W        = (const float*)d_in[6];
  float* out = (float*)d_out;

  // workspace layout (256B-aligned chunks)
  size_t off = 0;
  auto take = [&](size_t bytes) -> char* {
    char* p = (char*)d_ws + off;
    off += (bytes + 255) & ~(size_t)255;
    return p;
  };
  uint16_t* hb     = (uint16_t*)take((size_t)kN * kDOut * 2);         // 25.6 MB
  uint32_t* Wp     = (uint32_t*)take((size_t)kDIn * (kDOut / 2) * 4); // 64 KB
  int*      rowptr = (int*)take((size_t)(kN + 1) * 4);                // 400 KB
  int*      cnt8   = (int*)take((size_t)kCopies * kN * 4);            // 3.2 MB
  int*      cur    = (int*)take((size_t)kN * 4);                      // 400 KB
  int*      partials = (int*)take(64 * 4);
  uint2*    spack  = (uint2*)take((size_t)kNNZ * 8);                  // 25.6 MB
  const size_t csrNeeded = off;                                       // ~55.3 MB
  float*    Xd     = (float*)take((size_t)kN * kDIn * 4);             // 102.4 MB
  const size_t fullNeeded = off;                                      // ~157.7 MB
  if (ws_size < csrNeeded) return;
  const bool dense = (ws_size >= fullNeeded);

  const int edgeBlocks = (kNNZ + 255) / 256;
  const int spmmBlocks = (kN + 3) / 4;

  wpack_kernel<<<(kDIn * (kDOut / 2) + 255) / 256, 256, 0, stream>>>(W, Wp);

  // ---------- X: h = dropout(X) @ W -> hb (bf16) ----------
  if (dense) {
    hipMemsetAsync(Xd, 0, (size_t)kN * kDIn * 4, stream);
    scatteradd_kernel<<<edgeBlocks, 256, 0, stream>>>(x_rows, x_cols, x_vals, Xd, kNNZ);
    gemm_kernel<<<kN / 16, 1024, 0, stream>>>(Xd, Wp, (uint32_t*)hb);
  } else {
    hipMemsetAsync(cnt8, 0, (size_t)kCopies * kN * 4, stream);
    hist8_kernel<true><<<edgeBlocks, 256, 0, stream>>>(x_rows, cnt8, kNNZ);
    scan1_kernel<<<kScanBlk, 256, 0, stream>>>(cnt8, rowptr, partials, kN);
    scan2_kernel<<<1, 64, 0, stream>>>(partials, rowptr, kScanBlk, kN);
    scan3_kernel<<<(kN + 255) / 256, 256, 0, stream>>>(rowptr, cur, partials, kN);
    scatter_kernel<true><<<edgeBlocks, 256, 0, stream>>>(
        x_rows, x_cols, x_vals, cur, spack, kNNZ);
    spmm_csr_kernel<true, false><<<spmmBlocks, 256, 0, stream>>>(
        rowptr, spack, (const uint16_t*)Wp, hb, kN);
  }

  // ---------- adj: CSR build (hist8 + single-cur scatter) + spmm2(+relu) ----
  hipMemsetAsync(cnt8, 0, (size_t)kCopies * kN * 4, stream);
  hist8_kernel<false><<<edgeBlocks, 256, 0, stream>>>(adj_rows, cnt8, kNNZ);
  scan1_kernel<<<kScanBlk, 256, 0, stream>>>(cnt8, rowptr, partials, kN);
  scan2_kernel<<<1, 64, 0, stream>>>(partials, rowptr, kScanBlk, kN);
  scan3_kernel<<<(kN + 255) / 256, 256, 0, stream>>>(rowptr, cur, partials, kN);
  scatter_kernel<false><<<edgeBlocks, 256, 0, stream>>>(
      adj_rows, adj_cols, adj_vals, cur, spack, kNNZ);
  spmm_csr_kernel<false, true><<<spmmBlocks, 256, 0, stream>>>(
      rowptr, spack, hb, out, kN);
}